// Round 1
// baseline (279.772 us; speedup 1.0000x reference)
//
#include <hip/hip_runtime.h>
#include <stdint.h>

typedef unsigned short u16;
typedef __attribute__((ext_vector_type(8))) short short8;   // 8 x bf16 (4 VGPRs)
typedef __attribute__((ext_vector_type(4))) float f32x4;

__device__ __forceinline__ u16 f2b(float f){
  union { float f; unsigned u; } x; x.f = f;
  unsigned r = x.u + 0x7FFFu + ((x.u >> 16) & 1u);  // RNE
  return (u16)(r >> 16);
}

__device__ __forceinline__ void gload_lds16(const void* g, void* l){
  __builtin_amdgcn_global_load_lds(
      (const __attribute__((address_space(1))) unsigned int*)g,
      (__attribute__((address_space(3))) unsigned int*)l, 16, 0, 0);
}

// ---------------- weight transpose + cast: W[K][N] f32 -> WT[N][K] bf16 ----------------
__global__ void __launch_bounds__(256) transpose_cast(const float* __restrict__ in,
                                                      u16* __restrict__ out, int K, int N){
  __shared__ float sm[32][33];
  int k0 = blockIdx.x*32, n0 = blockIdx.y*32;
  int t = threadIdx.x; int tr = t>>5, tc = t&31;   // 8 x 32
  #pragma unroll
  for (int p=0;p<4;p++) sm[p*8+tr][tc] = in[(size_t)(k0+p*8+tr)*N + n0+tc];
  __syncthreads();
  #pragma unroll
  for (int p=0;p<4;p++) out[(size_t)(n0+p*8+tr)*K + k0+tc] = f2b(sm[tc][p*8+tr]);
}

// ---------------- bf16 transpose (per batch): in [4096][256] -> out [256][4096] --------
__global__ void __launch_bounds__(256) transpose_bf16(const u16* __restrict__ in,
                                                      u16* __restrict__ out){
  __shared__ u16 tile[64][72];  // pad 8 -> 144B stride (16B multiple)
  int b = blockIdx.z;
  const size_t S = 4096ull*256;
  const u16* I = in + (size_t)b*S; u16* O = out + (size_t)b*S;
  int r0 = blockIdx.x*64, c0 = blockIdx.y*64;
  int t = threadIdx.x;
  #pragma unroll
  for (int i=0;i<2;i++){
    int e = i*256 + t; int row = e>>3, ch = e&7;
    *(short8*)&tile[row][ch*8] = *(const short8*)(I + (size_t)(r0+row)*256 + c0 + ch*8);
  }
  __syncthreads();
  #pragma unroll
  for (int i=0;i<2;i++){
    int e = i*256 + t; int orow = e>>3, ch = e&7;
    short8 v;
    #pragma unroll
    for (int j=0;j<8;j++) v[j] = (short)tile[ch*8+j][orow];
    *(short8*)(O + (size_t)(c0+orow)*4096 + r0 + ch*8) = v;
  }
}

// ---------------- LayerNorm over D=256; one block per row --------------------------------
__global__ void __launch_bounds__(256) ln_kernel(const float* __restrict__ in,
                                                 const float* __restrict__ g,
                                                 const float* __restrict__ bb,
                                                 float* __restrict__ outF,
                                                 u16* __restrict__ outB){
  int row = blockIdx.x, t = threadIdx.x;
  size_t base = (size_t)row*256;
  float v = in[base + t];
  float s = v;
  #pragma unroll
  for (int m=1;m<64;m<<=1) s += __shfl_xor(s, m);
  __shared__ float red[4];
  int w = t>>6;
  if ((t&63)==0) red[w] = s;
  __syncthreads();
  float mean = (red[0]+red[1]+red[2]+red[3]) * (1.0f/256.0f);
  float d = v - mean;
  float s2 = d*d;
  #pragma unroll
  for (int m=1;m<64;m<<=1) s2 += __shfl_xor(s2, m);
  __syncthreads();
  if ((t&63)==0) red[w] = s2;
  __syncthreads();
  float var = (red[0]+red[1]+red[2]+red[3]) * (1.0f/256.0f);
  float y = d * rsqrtf(var + 1e-5f) * g[t] + bb[t];
  if (outF) outF[base+t] = y;
  outB[base+t] = f2b(y);
}

// ---------------- GEMM: C[M][N] = A_bf16[M][K] @ BT_bf16[N][K]^T + bias ------------------
// MODE 0: out bf16 ; MODE 1: relu -> bf16 ; MODE 2: + res -> f32
template<int MODE>
__global__ void __launch_bounds__(256, 2) gemm_bt(const u16* __restrict__ A,
                                                  const u16* __restrict__ BT,
                                                  const float* __restrict__ bias,
                                                  const float* __restrict__ res,
                                                  float* __restrict__ outF,
                                                  u16* __restrict__ outB,
                                                  int M, int N, int K){
  __shared__ u16 As[128*64];
  __shared__ u16 Bs[128*64];
  int tid = threadIdx.x;
  int m0 = blockIdx.x*128, n0 = blockIdx.y*128;
  int wave = tid>>6, lane = tid&63, lr = lane&15, lg = lane>>4;
  int wm = (wave>>1)*64, wn = (wave&1)*64;

  f32x4 acc[4][4];
  #pragma unroll
  for (int i=0;i<4;i++)
    #pragma unroll
    for (int j=0;j<4;j++) acc[i][j] = (f32x4){0.f,0.f,0.f,0.f};

  int nk = K >> 6;
  for (int kt=0; kt<nk; ++kt){
    __syncthreads();
    #pragma unroll
    for (int i=0;i<4;i++){
      int de = i*256 + tid; int row = de>>3; int ch = de&7; int sc = ch ^ (row&7);
      gload_lds16(A + (size_t)(m0+row)*K + kt*64 + sc*8, (char*)As + de*16);
    }
    #pragma unroll
    for (int i=0;i<4;i++){
      int de = i*256 + tid; int row = de>>3; int ch = de&7; int sc = ch ^ (row&7);
      gload_lds16(BT + (size_t)(n0+row)*K + kt*64 + sc*8, (char*)Bs + de*16);
    }
    asm volatile("s_waitcnt vmcnt(0)" ::: "memory");
    __syncthreads();
    #pragma unroll
    for (int kk=0;kk<2;kk++){
      short8 af[4], bf[4];
      #pragma unroll
      for (int mi=0;mi<4;mi++){
        int row = wm + mi*16 + lr;
        int c = (kk*4 + lg) ^ (row&7);
        af[mi] = *(const short8*)&As[row*64 + c*8];
      }
      #pragma unroll
      for (int ni=0;ni<4;ni++){
        int row = wn + ni*16 + lr;
        int c = (kk*4 + lg) ^ (row&7);
        bf[ni] = *(const short8*)&Bs[row*64 + c*8];
      }
      #pragma unroll
      for (int mi=0;mi<4;mi++)
        #pragma unroll
        for (int ni=0;ni<4;ni++)
          acc[mi][ni] = __builtin_amdgcn_mfma_f32_16x16x32_bf16(af[mi], bf[ni], acc[mi][ni], 0,0,0);
    }
  }
  #pragma unroll
  for (int mi=0;mi<4;mi++)
    #pragma unroll
    for (int ni=0;ni<4;ni++)
      #pragma unroll
      for (int r=0;r<4;r++){
        int row = m0 + wm + mi*16 + lg*4 + r;
        int col = n0 + wn + ni*16 + lr;
        float vout = acc[mi][ni][r] + bias[col];
        if (MODE==1) vout = fmaxf(vout, 0.f);
        if (MODE==2) outF[(size_t)row*N + col] = vout + res[(size_t)row*N + col];
        else         outB[(size_t)row*N + col] = f2b(vout);
      }
}

// ---------------- Flash attention, KV-split=2 --------------------------------------------
// grid (64, 4, 2); block 256. Q,K: [B*4096][256] bf16 ; VT: [B][256][4096] bf16.
// Opart: [split][B*4096][256] f32 ; ML: [split][B*4096][2] f32.
__global__ void __launch_bounds__(256, 2) flash_attn(const u16* __restrict__ Qb,
                                                     const u16* __restrict__ Kb,
                                                     const u16* __restrict__ VTb,
                                                     float* __restrict__ Opart,
                                                     float* __restrict__ MLpart){
  __shared__ u16 Ks[32*256];
  __shared__ u16 Vs[256*32];
  __shared__ u16 Ps[64*40];
  const int NC = 4096, D = 256;
  int tid = threadIdx.x, wave = tid>>6, lane = tid&63, lr = lane&15, lg = lane>>4;
  int b = blockIdx.y; int q0 = blockIdx.x*64; int s = blockIdx.z;
  int kvbeg = s*2048, kvend = kvbeg + 2048;

  // Q fragments in registers (16 rows per wave, K=256 -> 8 k-steps)
  short8 qf[8];
  const u16* qrow = Qb + (size_t)(b*NC + q0 + wave*16 + lr)*D;
  #pragma unroll
  for (int kk=0;kk<8;kk++) qf[kk] = *(const short8*)(qrow + kk*32 + lg*8);

  f32x4 o[16];
  #pragma unroll
  for (int i=0;i<16;i++) o[i] = (f32x4){0.f,0.f,0.f,0.f};
  float m[4], ell[4];
  #pragma unroll
  for (int r=0;r<4;r++){ m[r] = -__builtin_inff(); ell[r] = 0.f; }

  for (int kv0 = kvbeg; kv0 < kvend; kv0 += 32){
    __syncthreads();
    #pragma unroll
    for (int i=0;i<4;i++){   // K tile: 32 rows x 512B, swizzled source
      int de = i*256 + tid; int row = de>>5; int ch = de&31; int sc = ch ^ (row&7);
      gload_lds16(Kb + (size_t)(b*NC + kv0 + row)*D + sc*8, (char*)Ks + de*16);
    }
    #pragma unroll
    for (int i=0;i<4;i++){   // V^T tile: 256 rows x 64B, swizzled source
      int de = i*256 + tid; int row = de>>2; int ch = de&3; int sc = ch ^ (row&3);
      gload_lds16(VTb + (size_t)(b*D + row)*NC + kv0 + sc*8, (char*)Vs + de*16);
    }
    asm volatile("s_waitcnt vmcnt(0)" ::: "memory");
    __syncthreads();

    // S = Q K^T  (16 x 32 per wave)
    f32x4 sf0 = (f32x4){0.f,0.f,0.f,0.f}, sf1 = (f32x4){0.f,0.f,0.f,0.f};
    #pragma unroll
    for (int kk=0;kk<8;kk++){
      int c = kk*4 + lg;
      int cs = (c ^ (lr&7))*8;
      short8 k0 = *(const short8*)&Ks[lr*256 + cs];
      short8 k1 = *(const short8*)&Ks[(16+lr)*256 + cs];
      sf0 = __builtin_amdgcn_mfma_f32_16x16x32_bf16(qf[kk], k0, sf0, 0,0,0);
      sf1 = __builtin_amdgcn_mfma_f32_16x16x32_bf16(qf[kk], k1, sf1, 0,0,0);
    }

    // online softmax (rows = lg*4+r, cols across lanes 0..15 of each 16-group)
    float p0[4], p1[4], sc_[4];
    #pragma unroll
    for (int r=0;r<4;r++){
      float a = sf0[r]*0.0625f, c2 = sf1[r]*0.0625f;
      float rm = fmaxf(a, c2);
      #pragma unroll
      for (int mk=1; mk<16; mk<<=1) rm = fmaxf(rm, __shfl_xor(rm, mk));
      float mn = fmaxf(m[r], rm);
      sc_[r] = __expf(m[r] - mn);
      p0[r] = __expf(a - mn); p1[r] = __expf(c2 - mn);
      float rs = p0[r] + p1[r];
      #pragma unroll
      for (int mk=1; mk<16; mk<<=1) rs += __shfl_xor(rs, mk);
      ell[r] = ell[r]*sc_[r] + rs;
      m[r] = mn;
    }
    if (!__all(sc_[0]==1.f && sc_[1]==1.f && sc_[2]==1.f && sc_[3]==1.f)){
      #pragma unroll
      for (int dt=0; dt<16; dt++)
        #pragma unroll
        for (int r=0;r<4;r++) o[dt][r] *= sc_[r];
    }

    // P -> LDS (wave-private rows), then A-frag read
    #pragma unroll
    for (int r=0;r<4;r++){
      int prow = wave*16 + lg*4 + r;
      Ps[prow*40 + lr]      = f2b(p0[r]);
      Ps[prow*40 + 16 + lr] = f2b(p1[r]);
    }
    asm volatile("s_waitcnt lgkmcnt(0)" ::: "memory");
    short8 pa = *(const short8*)&Ps[(wave*16 + lr)*40 + lg*8];

    // O += P @ V
    #pragma unroll
    for (int dt=0; dt<16; dt++){
      int vrow = dt*16 + lr;
      int c = (lg ^ (vrow&3))*8;
      short8 vf = *(const short8*)&Vs[vrow*32 + c];
      o[dt] = __builtin_amdgcn_mfma_f32_16x16x32_bf16(pa, vf, o[dt], 0,0,0);
    }
  }

  size_t obase = ((size_t)s*4 + b)*NC + q0 + wave*16;
  #pragma unroll
  for (int dt=0; dt<16; dt++)
    #pragma unroll
    for (int r=0;r<4;r++)
      Opart[(obase + lg*4 + r)*256 + dt*16 + lr] = o[dt][r];
  if (lr == 0){
    #pragma unroll
    for (int r=0;r<4;r++){
      MLpart[(obase + lg*4 + r)*2]     = m[r];
      MLpart[(obase + lg*4 + r)*2 + 1] = ell[r];
    }
  }
}

// ---------------- merge split partials + residual(xln) -> x2 -----------------------------
__global__ void __launch_bounds__(256) attn_merge(const float* __restrict__ Opart,
                                                  const float* __restrict__ MLpart,
                                                  const float* __restrict__ xln,
                                                  float* __restrict__ x2){
  int row = blockIdx.x; int t = threadIdx.x;
  const size_t RS = 16384ull*256;
  float m0 = MLpart[(size_t)row*2],            l0 = MLpart[(size_t)row*2+1];
  float m1 = MLpart[(16384ull+row)*2],         l1 = MLpart[(16384ull+row)*2+1];
  float M  = fmaxf(m0, m1);
  float e0 = __expf(m0-M), e1 = __expf(m1-M);
  float inv = 1.0f / (l0*e0 + l1*e1);
  size_t idx = (size_t)row*256 + t;
  float v = (Opart[idx]*e0 + Opart[RS+idx]*e1) * inv;
  x2[idx] = v + xln[idx];
}

extern "C" void kernel_launch(void* const* d_in, const int* in_sizes, int n_in,
                              void* d_out, int out_size, void* d_ws, size_t ws_size,
                              hipStream_t stream){
  const float* x   = (const float*)d_in[0];
  const float* g1  = (const float*)d_in[1];
  const float* be1 = (const float*)d_in[2];
  const float* wq  = (const float*)d_in[3];
  const float* bq  = (const float*)d_in[4];
  const float* wk  = (const float*)d_in[5];
  const float* bk  = (const float*)d_in[6];
  const float* wv  = (const float*)d_in[7];
  const float* bv  = (const float*)d_in[8];
  const float* g2  = (const float*)d_in[9];
  const float* be2 = (const float*)d_in[10];
  const float* w1  = (const float*)d_in[11];
  const float* bm1 = (const float*)d_in[12];
  const float* w2  = (const float*)d_in[13];
  const float* bm2 = (const float*)d_in[14];
  float* out = (float*)d_out;

  const size_t RS = 16384ull*256;
  char* p = (char*)d_ws;
  float* xln = (float*)p;  p += RS*4;          // later reused in-place as x2
  float* Op  = (float*)p;  p += 2*RS*4;        // later reused as h1 (bf16)
  float* ML  = (float*)p;  p += 2*16384ull*2*4;
  u16* xb  = (u16*)p; p += RS*2;
  u16* qb  = (u16*)p; p += RS*2;
  u16* kb  = (u16*)p; p += RS*2;
  u16* vb  = (u16*)p; p += RS*2;
  u16* vT  = (u16*)p; p += RS*2;
  u16* h2  = (u16*)p; p += RS*2;
  u16* wqT = (u16*)p; p += 65536ull*2;
  u16* wkT = (u16*)p; p += 65536ull*2;
  u16* wvT = (u16*)p; p += 65536ull*2;
  u16* w1T = (u16*)p; p += 262144ull*2;
  u16* w2T = (u16*)p; p += 262144ull*2;
  float* x2 = xln;
  u16*   h1 = (u16*)Op;

  transpose_cast<<<dim3(8,8),  256,0,stream>>>(wq, wqT, 256, 256);
  transpose_cast<<<dim3(8,8),  256,0,stream>>>(wk, wkT, 256, 256);
  transpose_cast<<<dim3(8,8),  256,0,stream>>>(wv, wvT, 256, 256);
  transpose_cast<<<dim3(8,32), 256,0,stream>>>(w1, w1T, 256, 1024);
  transpose_cast<<<dim3(32,8), 256,0,stream>>>(w2, w2T, 1024, 256);

  ln_kernel<<<16384,256,0,stream>>>(x, g1, be1, xln, xb);

  gemm_bt<0><<<dim3(128,2),256,0,stream>>>(xb, wqT, bq, nullptr, nullptr, qb, 16384,256,256);
  gemm_bt<0><<<dim3(128,2),256,0,stream>>>(xb, wkT, bk, nullptr, nullptr, kb, 16384,256,256);
  gemm_bt<0><<<dim3(128,2),256,0,stream>>>(xb, wvT, bv, nullptr, nullptr, vb, 16384,256,256);

  transpose_bf16<<<dim3(64,4,4),256,0,stream>>>(vb, vT);

  flash_attn<<<dim3(64,4,2),256,0,stream>>>(qb, kb, vT, Op, ML);
  attn_merge<<<16384,256,0,stream>>>(Op, ML, xln, x2);

  ln_kernel<<<16384,256,0,stream>>>(x2, g2, be2, nullptr, h2);

  gemm_bt<1><<<dim3(128,8),256,0,stream>>>(h2, w1T, bm1, nullptr, nullptr, h1, 16384,1024,256);
  gemm_bt<2><<<dim3(128,2),256,0,stream>>>(h1, w2T, bm2, x2, out, nullptr, 16384,256,1024);
}

// Round 4
// 198.362 us; speedup vs baseline: 1.4104x; 1.4104x over previous
//
#include <hip/hip_runtime.h>
#include <stdint.h>

typedef unsigned short u16;
typedef __attribute__((ext_vector_type(8))) short short8;   // 8 x bf16 (4 VGPRs)
typedef __attribute__((ext_vector_type(4))) float f32x4;
typedef __attribute__((ext_vector_type(16))) float f32x16;

__device__ __forceinline__ u16 f2b(float f){
  union { float f; unsigned u; } x; x.f = f;
  unsigned r = x.u + 0x7FFFu + ((x.u >> 16) & 1u);  // RNE
  return (u16)(r >> 16);
}

__device__ __forceinline__ unsigned cvtpk_bf16(float lo, float hi){
  unsigned r;
  asm("v_cvt_pk_bf16_f32 %0, %1, %2" : "=v"(r) : "v"(lo), "v"(hi));
  return r;
}

__device__ __forceinline__ void gload_lds16(const void* g, void* l){
  __builtin_amdgcn_global_load_lds(
      (const __attribute__((address_space(1))) unsigned int*)g,
      (__attribute__((address_space(3))) unsigned int*)l, 16, 0, 0);
}

// ---------------- weight transpose + cast: W[K][N] f32 -> WT[N][K] bf16 ----------------
__global__ void __launch_bounds__(256) transpose_cast(const float* __restrict__ in,
                                                      u16* __restrict__ out, int K, int N){
  __shared__ float sm[32][33];
  int k0 = blockIdx.x*32, n0 = blockIdx.y*32;
  int t = threadIdx.x; int tr = t>>5, tc = t&31;   // 8 x 32
  #pragma unroll
  for (int p=0;p<4;p++) sm[p*8+tr][tc] = in[(size_t)(k0+p*8+tr)*N + n0+tc];
  __syncthreads();
  #pragma unroll
  for (int p=0;p<4;p++) out[(size_t)(n0+p*8+tr)*K + k0+tc] = f2b(sm[tc][p*8+tr]);
}

// ------- bf16 V retile (per batch): in [4096 n][256 d] -> out granules [n/8][256 d][8 n]
__global__ void __launch_bounds__(256) retile_v(const u16* __restrict__ in,
                                                u16* __restrict__ out){
  __shared__ u16 tile[64][72];  // pad 8
  int b = blockIdx.z;
  const size_t S = 4096ull*256;
  const u16* I = in + (size_t)b*S; u16* O = out + (size_t)b*S;
  int r0 = blockIdx.x*64, c0 = blockIdx.y*64;   // r0: n-tile, c0: d-tile
  int t = threadIdx.x;
  #pragma unroll
  for (int i=0;i<2;i++){
    int e = i*256 + t; int row = e>>3, ch = e&7;
    *(short8*)&tile[row][ch*8] = *(const short8*)(I + (size_t)(r0+row)*256 + c0 + ch*8);
  }
  __syncthreads();
  #pragma unroll
  for (int i=0;i<2;i++){
    int e = i*256 + t; int orow = e>>3, ch = e&7;   // orow: d within tile, ch: n-chunk
    short8 v;
    #pragma unroll
    for (int j=0;j<8;j++) v[j] = (short)tile[ch*8+j][orow];
    // granule index = (n>>3)*256 + d ; element = n&7
    *(short8*)(O + (((size_t)((r0>>3)+ch)*256 + (size_t)(c0+orow))<<3)) = v;
  }
}

// ---------------- LayerNorm over D=256; one block per row --------------------------------
__global__ void __launch_bounds__(256) ln_kernel(const float* __restrict__ in,
                                                 const float* __restrict__ g,
                                                 const float* __restrict__ bb,
                                                 float* __restrict__ outF,
                                                 u16* __restrict__ outB){
  int row = blockIdx.x, t = threadIdx.x;
  size_t base = (size_t)row*256;
  float v = in[base + t];
  float s = v;
  #pragma unroll
  for (int m=1;m<64;m<<=1) s += __shfl_xor(s, m);
  __shared__ float red[4];
  int w = t>>6;
  if ((t&63)==0) red[w] = s;
  __syncthreads();
  float mean = (red[0]+red[1]+red[2]+red[3]) * (1.0f/256.0f);
  float d = v - mean;
  float s2 = d*d;
  #pragma unroll
  for (int m=1;m<64;m<<=1) s2 += __shfl_xor(s2, m);
  __syncthreads();
  if ((t&63)==0) red[w] = s2;
  __syncthreads();
  float var = (red[0]+red[1]+red[2]+red[3]) * (1.0f/256.0f);
  float y = d * rsqrtf(var + 1e-5f) * g[t] + bb[t];
  if (outF) outF[base+t] = y;
  outB[base+t] = f2b(y);
}

// ---------------- GEMM: C[M][N] = A_bf16[M][K] @ BT_bf16[N][K]^T + bias ------------------
// MODE 0: out bf16 ; MODE 1: relu -> bf16 ; MODE 2: + res -> f32
template<int MODE>
__global__ void __launch_bounds__(256, 2) gemm_bt(const u16* __restrict__ A,
                                                  const u16* __restrict__ BT,
                                                  const float* __restrict__ bias,
                                                  const float* __restrict__ res,
                                                  float* __restrict__ outF,
                                                  u16* __restrict__ outB,
                                                  int M, int N, int K){
  __shared__ u16 As[128*64];
  __shared__ u16 Bs[128*64];
  int tid = threadIdx.x;
  int m0 = blockIdx.x*128, n0 = blockIdx.y*128;
  int wave = tid>>6, lane = tid&63, lr = lane&15, lg = lane>>4;
  int wm = (wave>>1)*64, wn = (wave&1)*64;

  f32x4 acc[4][4];
  #pragma unroll
  for (int i=0;i<4;i++)
    #pragma unroll
    for (int j=0;j<4;j++) acc[i][j] = (f32x4){0.f,0.f,0.f,0.f};

  int nk = K >> 6;
  for (int kt=0; kt<nk; ++kt){
    __syncthreads();
    #pragma unroll
    for (int i=0;i<4;i++){
      int de = i*256 + tid; int row = de>>3; int ch = de&7; int sc = ch ^ (row&7);
      gload_lds16(A + (size_t)(m0+row)*K + kt*64 + sc*8, (char*)As + de*16);
    }
    #pragma unroll
    for (int i=0;i<4;i++){
      int de = i*256 + tid; int row = de>>3; int ch = de&7; int sc = ch ^ (row&7);
      gload_lds16(BT + (size_t)(n0+row)*K + kt*64 + sc*8, (char*)Bs + de*16);
    }
    asm volatile("s_waitcnt vmcnt(0)" ::: "memory");
    __syncthreads();
    #pragma unroll
    for (int kk=0;kk<2;kk++){
      short8 af[4], bf[4];
      #pragma unroll
      for (int mi=0;mi<4;mi++){
        int row = wm + mi*16 + lr;
        int c = (kk*4 + lg) ^ (row&7);
        af[mi] = *(const short8*)&As[row*64 + c*8];
      }
      #pragma unroll
      for (int ni=0;ni<4;ni++){
        int row = wn + ni*16 + lr;
        int c = (kk*4 + lg) ^ (row&7);
        bf[ni] = *(const short8*)&Bs[row*64 + c*8];
      }
      #pragma unroll
      for (int mi=0;mi<4;mi++)
        #pragma unroll
        for (int ni=0;ni<4;ni++)
          acc[mi][ni] = __builtin_amdgcn_mfma_f32_16x16x32_bf16(af[mi], bf[ni], acc[mi][ni], 0,0,0);
    }
  }
  #pragma unroll
  for (int mi=0;mi<4;mi++)
    #pragma unroll
    for (int ni=0;ni<4;ni++)
      #pragma unroll
      for (int r=0;r<4;r++){
        int row = m0 + wm + mi*16 + lg*4 + r;
        int col = n0 + wn + ni*16 + lr;
        float vout = acc[mi][ni][r] + bias[col];
        if (MODE==1) vout = fmaxf(vout, 0.f);
        if (MODE==2) outF[(size_t)row*N + col] = vout + res[(size_t)row*N + col];
        else         outB[(size_t)row*N + col] = f2b(vout);
      }
}

// ---------------- Flash attention, 32x32 MFMA, swapped QK^T, P via LDS -------------------
// grid (32, B=4, SPLIT=4); block 256 (4 waves x 32 q-rows = 128 q / block).
// Q,K: [B*4096][256] bf16 ; Vt granules: [B][512][256][8] bf16.
// Opart: [split][B*4096][256] bf16 ; ML: [split][B*4096][2] f32.
__device__ __forceinline__ void stage_tiles(const u16* __restrict__ Kb,
                                            const u16* __restrict__ Vt,
                                            int b, int kv0,
                                            char* Kdst, char* Vdst, int tid){
  #pragma unroll
  for (int i=0;i<4;i++){
    int de = i*256 + tid; int kv = de>>5; int c = de&31; int sc = c ^ (kv&7);
    gload_lds16(Kb + (((size_t)(b*4096 + kv0 + kv))<<8) + sc*8, Kdst + (size_t)de*16);
  }
  #pragma unroll
  for (int i=0;i<4;i++){
    int de = i*256 + tid; int kvc = de>>8; int d = de&255;
    gload_lds16(Vt + ((((size_t)b*512 + (kv0>>3) + kvc)<<8) + (size_t)d)*8,
                Vdst + (size_t)de*16);
  }
}

__global__ void __launch_bounds__(256, 2) flash_attn32(const u16* __restrict__ Qb,
                                                       const u16* __restrict__ Kb,
                                                       const u16* __restrict__ Vt,
                                                       u16* __restrict__ Opart,
                                                       float* __restrict__ MLpart){
  // [K0 16K][V0 16K][K1 16K][V1 16K][Ps 10K]
  __shared__ __align__(16) char smem[75776];
  const int NC = 4096;
  int tid = threadIdx.x, wave = tid>>6, lane = tid&63;
  int lq = lane & 31, hi = lane >> 5;
  int b = blockIdx.y, s = blockIdx.z;
  int qb0 = blockIdx.x*128 + wave*32;
  int kvbeg = s*1024;
  const int NT = 32;
  u16* PsW = (u16*)(smem + 65536) + wave*32*40;   // wave-private P: [32 q][40 stride]

  // Q B-frags in registers: lane holds Q[q = qb0+lq][ks*16 + hi*8 .. +7]
  short8 qf[16];
  {
    const u16* qbase = Qb + (((size_t)b*NC + qb0 + lq)<<8) + hi*8;
    #pragma unroll
    for (int ks=0; ks<16; ks++) qf[ks] = *(const short8*)(qbase + ks*16);
  }

  f32x16 o[8];
  #pragma unroll
  for (int i=0;i<8;i++)
    o[i] = (f32x16){0.f,0.f,0.f,0.f,0.f,0.f,0.f,0.f,0.f,0.f,0.f,0.f,0.f,0.f,0.f,0.f};
  float mrun = -__builtin_inff(), ell = 0.f;

  stage_tiles(Kb, Vt, b, kvbeg, smem, smem + 16384, tid);
  asm volatile("s_waitcnt vmcnt(0)" ::: "memory");
  __syncthreads();

  for (int t=0; t<NT; t++){
    char* Kc = smem + ((t&1) ? 32768 : 0);
    char* Vc = Kc + 16384;
    char* Kn = smem + ((t&1) ? 0 : 32768);
    char* Vn = Kn + 16384;
    int kv0 = kvbeg + t*32;
    if (t+1 < NT) stage_tiles(Kb, Vt, b, kv0+32, Kn, Vn, tid);

    // ---- S^T = K @ Q^T : lane holds S[q=lq][kv=(r&3)+8*(r>>2)+4*hi] ----
    f32x16 sacc = (f32x16){0.f,0.f,0.f,0.f,0.f,0.f,0.f,0.f,0.f,0.f,0.f,0.f,0.f,0.f,0.f,0.f};
    __builtin_amdgcn_s_setprio(1);
    #pragma unroll
    for (int ks=0; ks<16; ks++){
      int c = ks*2 + hi;
      short8 kf = *(const short8*)(Kc + lq*512 + ((c ^ (lq&7))<<4));
      sacc = __builtin_amdgcn_mfma_f32_32x32x16_bf16(kf, qf[ks], sacc, 0,0,0);
    }
    __builtin_amdgcn_s_setprio(0);

    // ---- online softmax, one q per lane ----
    float tmax = sacc[0];
    #pragma unroll
    for (int r=1;r<16;r++) tmax = fmaxf(tmax, sacc[r]);
    tmax *= 0.0625f;
    tmax = fmaxf(tmax, __shfl_xor(tmax, 32));
    if (!__all(tmax <= mrun + 8.f)){           // T13 defer-max
      float mn = fmaxf(mrun, tmax);
      float sc = __expf(mrun - mn);
      mrun = mn; ell *= sc;
      #pragma unroll
      for (int r=0;r<16;r++){
        float scr = __shfl(sc, (r&3)+8*(r>>2)+4*hi);
        #pragma unroll
        for (int dt=0; dt<8; dt++) o[dt][r] *= scr;
      }
    }

    // ---- P -> wave-private LDS at verified C-layout coords, then A-frag reads ----
    // lane (lq,hi), h half: p[r] = P[q=lq][kv = (r&3) + 8*(r>>2) + 4*hi + 16*h]
    float rs = 0.f;
    #pragma unroll
    for (int h=0; h<2; h++){
      float p[8];
      #pragma unroll
      for (int r=0;r<8;r++){ p[r] = __expf(sacc[h*8+r]*0.0625f - mrun); rs += p[r]; }
      uint2 w0, w1;
      w0.x = cvtpk_bf16(p[0], p[1]);  w0.y = cvtpk_bf16(p[2], p[3]);   // kv (0..3)+4hi+16h
      w1.x = cvtpk_bf16(p[4], p[5]);  w1.y = cvtpk_bf16(p[6], p[7]);   // kv (8..11)+4hi+16h
      *(uint2*)(PsW + lq*40 + h*16 + hi*4)     = w0;
      *(uint2*)(PsW + lq*40 + h*16 + 8 + hi*4) = w1;
    }
    rs += __shfl_xor(rs, 32);
    ell += rs;
    asm volatile("s_waitcnt lgkmcnt(0)" ::: "memory");
    __builtin_amdgcn_sched_barrier(0);
    short8 pa0 = *(const short8*)(PsW + lq*40 + hi*8);        // P[lq][hi*8 + 0..7]
    short8 pa1 = *(const short8*)(PsW + lq*40 + 16 + hi*8);   // P[lq][16 + hi*8 + 0..7]

    // ---- O += P @ V ----
    __builtin_amdgcn_s_setprio(1);
    #pragma unroll
    for (int dt=0; dt<8; dt++){
      short8 vf0 = *(const short8*)(Vc + (((hi  )*256 + dt*32 + lq)<<4));
      short8 vf1 = *(const short8*)(Vc + (((2+hi)*256 + dt*32 + lq)<<4));
      o[dt] = __builtin_amdgcn_mfma_f32_32x32x16_bf16(pa0, vf0, o[dt], 0,0,0);
      o[dt] = __builtin_amdgcn_mfma_f32_32x32x16_bf16(pa1, vf1, o[dt], 0,0,0);
    }
    __builtin_amdgcn_s_setprio(0);

    asm volatile("s_waitcnt vmcnt(0)" ::: "memory");
    __syncthreads();   // next tile staged + all waves done with cur
  }

  // ---- write partials (bf16) ----
  size_t rowb = (size_t)s*16384 + (size_t)b*NC + qb0;
  #pragma unroll
  for (int dt=0; dt<8; dt++)
    #pragma unroll
    for (int r=0;r<16;r++){
      int q = (r&3) + 8*(r>>2) + 4*hi;
      Opart[(rowb + q)*256 + dt*32 + lq] = f2b(o[dt][r]);
    }
  if (lane < 32){
    MLpart[(rowb + lane)*2]     = mrun;
    MLpart[(rowb + lane)*2 + 1] = ell;
  }
}

// ---------------- merge 4 split partials (bf16) + residual(xln) -> x2 --------------------
__global__ void __launch_bounds__(256) attn_merge4(const u16* __restrict__ Opart,
                                                   const float* __restrict__ MLpart,
                                                   const float* __restrict__ xln,
                                                   float* __restrict__ x2){
  int row = blockIdx.x; int t = threadIdx.x;
  const size_t RS = 16384ull*256;
  float m[4], l[4];
  #pragma unroll
  for (int s=0;s<4;s++){
    m[s] = MLpart[((size_t)s*16384 + row)*2];
    l[s] = MLpart[((size_t)s*16384 + row)*2 + 1];
  }
  float M = fmaxf(fmaxf(m[0],m[1]), fmaxf(m[2],m[3]));
  float e[4]; float den = 0.f;
  #pragma unroll
  for (int s=0;s<4;s++){ e[s] = __expf(m[s]-M); den += l[s]*e[s]; }
  float inv = 1.0f/den;
  size_t idx = (size_t)row*256 + t;
  float v = 0.f;
  #pragma unroll
  for (int s=0;s<4;s++){
    unsigned u = Opart[(size_t)s*RS + idx];
    v += __uint_as_float(u << 16) * e[s];
  }
  x2[idx] = v*inv + xln[idx];
}

extern "C" void kernel_launch(void* const* d_in, const int* in_sizes, int n_in,
                              void* d_out, int out_size, void* d_ws, size_t ws_size,
                              hipStream_t stream){
  const float* x   = (const float*)d_in[0];
  const float* g1  = (const float*)d_in[1];
  const float* be1 = (const float*)d_in[2];
  const float* wq  = (const float*)d_in[3];
  const float* bq  = (const float*)d_in[4];
  const float* wk  = (const float*)d_in[5];
  const float* bk  = (const float*)d_in[6];
  const float* wv  = (const float*)d_in[7];
  const float* bv  = (const float*)d_in[8];
  const float* g2  = (const float*)d_in[9];
  const float* be2 = (const float*)d_in[10];
  const float* w1  = (const float*)d_in[11];
  const float* bm1 = (const float*)d_in[12];
  const float* w2  = (const float*)d_in[13];
  const float* bm2 = (const float*)d_in[14];
  float* out = (float*)d_out;

  // ws budget ~90 MiB (round-1-proven 98 MiB worked)
  const size_t RS = 16384ull*256;
  char* p = (char*)d_ws;
  float* xln = (float*)p;  p += RS*4;            // 16 MiB; reused in-place as x2
  u16*  Op   = (u16*)p;    p += 4*RS*2;          // 32 MiB bf16 partials; reused as h1
  float* ML  = (float*)p;  p += 4*16384ull*2*4;  // 0.5 MiB
  u16* xb  = (u16*)p; p += RS*2;                 // 8 MiB
  u16* qb  = (u16*)p; p += RS*2;                 // 8 MiB; reused as h2 after flash
  u16* kb  = (u16*)p; p += RS*2;
  u16* vb  = (u16*)p; p += RS*2;
  u16* vT  = (u16*)p; p += RS*2;
  u16* wqT = (u16*)p; p += 65536ull*2;
  u16* wkT = (u16*)p; p += 65536ull*2;
  u16* wvT = (u16*)p; p += 65536ull*2;
  u16* w1T = (u16*)p; p += 262144ull*2;
  u16* w2T = (u16*)p; p += 262144ull*2;
  float* x2 = xln;
  u16*   h1 = Op;
  u16*   h2 = qb;

  transpose_cast<<<dim3(8,8),  256,0,stream>>>(wq, wqT, 256, 256);
  transpose_cast<<<dim3(8,8),  256,0,stream>>>(wk, wkT, 256, 256);
  transpose_cast<<<dim3(8,8),  256,0,stream>>>(wv, wvT, 256, 256);
  transpose_cast<<<dim3(8,32), 256,0,stream>>>(w1, w1T, 256, 1024);
  transpose_cast<<<dim3(32,8), 256,0,stream>>>(w2, w2T, 1024, 256);

  ln_kernel<<<16384,256,0,stream>>>(x, g1, be1, xln, xb);

  gemm_bt<0><<<dim3(128,2),256,0,stream>>>(xb, wqT, bq, nullptr, nullptr, qb, 16384,256,256);
  gemm_bt<0><<<dim3(128,2),256,0,stream>>>(xb, wkT, bk, nullptr, nullptr, kb, 16384,256,256);
  gemm_bt<0><<<dim3(128,2),256,0,stream>>>(xb, wvT, bv, nullptr, nullptr, vb, 16384,256,256);

  retile_v<<<dim3(64,4,4),256,0,stream>>>(vb, vT);

  flash_attn32<<<dim3(32,4,4),256,0,stream>>>(qb, kb, vT, Op, ML);
  attn_merge4<<<16384,256,0,stream>>>(Op, ML, xln, x2);

  ln_kernel<<<16384,256,0,stream>>>(x2, g2, be2, nullptr, h2);

  gemm_bt<1><<<dim3(128,8),256,0,stream>>>(h2, w1T, bm1, nullptr, nullptr, h1, 16384,1024,256);
  gemm_bt<2><<<dim3(128,2),256,0,stream>>>(h1, w2T, bm2, x2, out, nullptr, 16384,256,1024);
}

// Round 6
// 173.231 us; speedup vs baseline: 1.6150x; 1.1451x over previous
//
#include <hip/hip_runtime.h>
#include <stdint.h>

typedef unsigned short u16;
typedef __attribute__((ext_vector_type(8))) short short8;   // 8 x bf16 (4 VGPRs)
typedef __attribute__((ext_vector_type(4))) float f32x4;
typedef __attribute__((ext_vector_type(16))) float f32x16;

__device__ __forceinline__ u16 f2b(float f){
  union { float f; unsigned u; } x; x.f = f;
  unsigned r = x.u + 0x7FFFu + ((x.u >> 16) & 1u);  // RNE
  return (u16)(r >> 16);
}

__device__ __forceinline__ unsigned cvtpk_bf16(float lo, float hi){
  unsigned r;
  asm("v_cvt_pk_bf16_f32 %0, %1, %2" : "=v"(r) : "v"(lo), "v"(hi));
  return r;
}

__device__ __forceinline__ void gload_lds16(const void* g, void* l){
  __builtin_amdgcn_global_load_lds(
      (const __attribute__((address_space(1))) unsigned int*)g,
      (__attribute__((address_space(3))) unsigned int*)l, 16, 0, 0);
}

// -------- weight transpose + cast: W[K][N] f32 -> WT[N][K] bf16 (generic) ---------------
__global__ void __launch_bounds__(256) transpose_cast(const float* __restrict__ in,
                                                      u16* __restrict__ out, int K, int N){
  __shared__ float sm[32][33];
  int k0 = blockIdx.x*32, n0 = blockIdx.y*32;
  int t = threadIdx.x; int tr = t>>5, tc = t&31;   // 8 x 32
  #pragma unroll
  for (int p=0;p<4;p++) sm[p*8+tr][tc] = in[(size_t)(k0+p*8+tr)*N + n0+tc];
  __syncthreads();
  #pragma unroll
  for (int p=0;p<4;p++) out[(size_t)(n0+p*8+tr)*K + k0+tc] = f2b(sm[tc][p*8+tr]);
}

// -------- QKV weight transpose: wq/wk/wv [256][256] -> wqkvT[768][256] bf16 -------------
__global__ void __launch_bounds__(256) transpose_cast3(const float* __restrict__ wq,
                                                       const float* __restrict__ wk,
                                                       const float* __restrict__ wv,
                                                       u16* __restrict__ out){
  __shared__ float sm[32][33];
  int z = blockIdx.z;
  const float* in = (z==0) ? wq : (z==1) ? wk : wv;
  u16* o = out + (size_t)z*65536;
  int k0 = blockIdx.x*32, n0 = blockIdx.y*32;
  int t = threadIdx.x; int tr = t>>5, tc = t&31;
  #pragma unroll
  for (int p=0;p<4;p++) sm[p*8+tr][tc] = in[(size_t)(k0+p*8+tr)*256 + n0+tc];
  __syncthreads();
  #pragma unroll
  for (int p=0;p<4;p++) o[(size_t)(n0+p*8+tr)*256 + k0+tc] = f2b(sm[tc][p*8+tr]);
}

// ---------------- LayerNorm over D=256; one block per row --------------------------------
__global__ void __launch_bounds__(256) ln_kernel(const float* __restrict__ in,
                                                 const float* __restrict__ g,
                                                 const float* __restrict__ bb,
                                                 float* __restrict__ outF,
                                                 u16* __restrict__ outB){
  int row = blockIdx.x, t = threadIdx.x;
  size_t base = (size_t)row*256;
  float v = in[base + t];
  float s = v;
  #pragma unroll
  for (int m=1;m<64;m<<=1) s += __shfl_xor(s, m);
  __shared__ float red[4];
  int w = t>>6;
  if ((t&63)==0) red[w] = s;
  __syncthreads();
  float mean = (red[0]+red[1]+red[2]+red[3]) * (1.0f/256.0f);
  float d = v - mean;
  float s2 = d*d;
  #pragma unroll
  for (int m=1;m<64;m<<=1) s2 += __shfl_xor(s2, m);
  __syncthreads();
  if ((t&63)==0) red[w] = s2;
  __syncthreads();
  float var = (red[0]+red[1]+red[2]+red[3]) * (1.0f/256.0f);
  float y = d * rsqrtf(var + 1e-5f) * g[t] + bb[t];
  if (outF) outF[base+t] = y;
  outB[base+t] = f2b(y);
}

// ---------------- GEMM: C[M][N] = A_bf16[M][K] @ BT_bf16[N][K]^T + bias ------------------
// MODE 0: out bf16 ; MODE 1: relu -> bf16 ; MODE 2: + res -> f32
// MODE 3: fused QKV: N=768, seg=n0>>8 -> 0: qb, 1: kb, 2: V granules
template<int MODE>
__global__ void __launch_bounds__(256, 2) gemm_bt(const u16* __restrict__ A,
                                                  const u16* __restrict__ BT,
                                                  const float* __restrict__ bias,
                                                  const float* __restrict__ bias2,
                                                  const float* __restrict__ bias3,
                                                  const float* __restrict__ res,
                                                  float* __restrict__ outF,
                                                  u16* __restrict__ outB,
                                                  u16* __restrict__ outB2,
                                                  u16* __restrict__ outB3,
                                                  int M, int N, int K){
  __shared__ u16 As[128*64];
  __shared__ u16 Bs[128*64];
  int tid = threadIdx.x;
  int m0 = blockIdx.x*128, n0 = blockIdx.y*128;
  int wave = tid>>6, lane = tid&63, lr = lane&15, lg = lane>>4;
  int wm = (wave>>1)*64, wn = (wave&1)*64;

  f32x4 acc[4][4];
  #pragma unroll
  for (int i=0;i<4;i++)
    #pragma unroll
    for (int j=0;j<4;j++) acc[i][j] = (f32x4){0.f,0.f,0.f,0.f};

  int nk = K >> 6;
  for (int kt=0; kt<nk; ++kt){
    __syncthreads();
    #pragma unroll
    for (int i=0;i<4;i++){
      int de = i*256 + tid; int row = de>>3; int ch = de&7; int sc = ch ^ (row&7);
      gload_lds16(A + (size_t)(m0+row)*K + kt*64 + sc*8, (char*)As + de*16);
    }
    #pragma unroll
    for (int i=0;i<4;i++){
      int de = i*256 + tid; int row = de>>3; int ch = de&7; int sc = ch ^ (row&7);
      gload_lds16(BT + (size_t)(n0+row)*K + kt*64 + sc*8, (char*)Bs + de*16);
    }
    asm volatile("s_waitcnt vmcnt(0)" ::: "memory");
    __syncthreads();
    #pragma unroll
    for (int kk=0;kk<2;kk++){
      short8 af[4], bf[4];
      #pragma unroll
      for (int mi=0;mi<4;mi++){
        int row = wm + mi*16 + lr;
        int c = (kk*4 + lg) ^ (row&7);
        af[mi] = *(const short8*)&As[row*64 + c*8];
      }
      #pragma unroll
      for (int ni=0;ni<4;ni++){
        int row = wn + ni*16 + lr;
        int c = (kk*4 + lg) ^ (row&7);
        bf[ni] = *(const short8*)&Bs[row*64 + c*8];
      }
      #pragma unroll
      for (int mi=0;mi<4;mi++)
        #pragma unroll
        for (int ni=0;ni<4;ni++)
          acc[mi][ni] = __builtin_amdgcn_mfma_f32_16x16x32_bf16(af[mi], bf[ni], acc[mi][ni], 0,0,0);
    }
  }
  #pragma unroll
  for (int mi=0;mi<4;mi++)
    #pragma unroll
    for (int ni=0;ni<4;ni++)
      #pragma unroll
      for (int r=0;r<4;r++){
        int row = m0 + wm + mi*16 + lg*4 + r;
        int col = n0 + wn + ni*16 + lr;
        if (MODE==3){
          int seg = n0 >> 8;
          int c2 = col & 255;
          float bb = (seg==0) ? bias[c2] : (seg==1) ? bias2[c2] : bias3[c2];
          float vout = acc[mi][ni][r] + bb;
          if (seg==0)      outB [(size_t)row*256 + c2] = f2b(vout);
          else if (seg==1) outB2[(size_t)row*256 + c2] = f2b(vout);
          else {
            // V granule: [b][n/8][256 d][8 n]
            size_t gaddr = ((size_t)(row>>12)<<20)
                         + ((((size_t)((row&4095)>>3)<<8) + (size_t)c2)<<3) + (row&7);
            outB3[gaddr] = f2b(vout);
          }
        } else {
          float vout = acc[mi][ni][r] + bias[col];
          if (MODE==1) vout = fmaxf(vout, 0.f);
          if (MODE==2) outF[(size_t)row*N + col] = vout + res[(size_t)row*N + col];
          else         outB[(size_t)row*N + col] = f2b(vout);
        }
      }
}

// ---------------- Flash attention (ROUND-4 PROVEN VERSION, verbatim) ---------------------
// grid (32, B=4, SPLIT=4); block 256 (4 waves x 32 q-rows = 128 q / block).
// Q,K: [B*4096][256] bf16 ; Vt granules: [B][512][256][8] bf16.
// Opart: [split][B*4096][256] bf16 ; ML: [split][B*4096][2] f32.
__device__ __forceinline__ void stage_tiles(const u16* __restrict__ Kb,
                                            const u16* __restrict__ Vt,
                                            int b, int kv0,
                                            char* Kdst, char* Vdst, int tid){
  #pragma unroll
  for (int i=0;i<4;i++){
    int de = i*256 + tid; int kv = de>>5; int c = de&31; int sc = c ^ (kv&7);
    gload_lds16(Kb + (((size_t)(b*4096 + kv0 + kv))<<8) + sc*8, Kdst + (size_t)de*16);
  }
  #pragma unroll
  for (int i=0;i<4;i++){
    int de = i*256 + tid; int kvc = de>>8; int d = de&255;
    gload_lds16(Vt + ((((size_t)b*512 + (kv0>>3) + kvc)<<8) + (size_t)d)*8,
                Vdst + (size_t)de*16);
  }
}

__global__ void __launch_bounds__(256, 2) flash_attn32(const u16* __restrict__ Qb,
                                                       const u16* __restrict__ Kb,
                                                       const u16* __restrict__ Vt,
                                                       u16* __restrict__ Opart,
                                                       float* __restrict__ MLpart){
  // [K0 16K][V0 16K][K1 16K][V1 16K][Ps 10K]
  __shared__ __align__(16) char smem[75776];
  const int NC = 4096;
  int tid = threadIdx.x, wave = tid>>6, lane = tid&63;
  int lq = lane & 31, hi = lane >> 5;
  int b = blockIdx.y, s = blockIdx.z;
  int qb0 = blockIdx.x*128 + wave*32;
  int kvbeg = s*1024;
  const int NT = 32;
  u16* PsW = (u16*)(smem + 65536) + wave*32*40;   // wave-private P: [32 q][40 stride]

  // Q B-frags in registers: lane holds Q[q = qb0+lq][ks*16 + hi*8 .. +7]
  short8 qf[16];
  {
    const u16* qbase = Qb + (((size_t)b*NC + qb0 + lq)<<8) + hi*8;
    #pragma unroll
    for (int ks=0; ks<16; ks++) qf[ks] = *(const short8*)(qbase + ks*16);
  }

  f32x16 o[8];
  #pragma unroll
  for (int i=0;i<8;i++)
    o[i] = (f32x16){0.f,0.f,0.f,0.f,0.f,0.f,0.f,0.f,0.f,0.f,0.f,0.f,0.f,0.f,0.f,0.f};
  float mrun = -__builtin_inff(), ell = 0.f;

  stage_tiles(Kb, Vt, b, kvbeg, smem, smem + 16384, tid);
  asm volatile("s_waitcnt vmcnt(0)" ::: "memory");
  __syncthreads();

  for (int t=0; t<NT; t++){
    char* Kc = smem + ((t&1) ? 32768 : 0);
    char* Vc = Kc + 16384;
    char* Kn = smem + ((t&1) ? 0 : 32768);
    char* Vn = Kn + 16384;
    int kv0 = kvbeg + t*32;
    if (t+1 < NT) stage_tiles(Kb, Vt, b, kv0+32, Kn, Vn, tid);

    // ---- S^T = K @ Q^T : lane holds S[q=lq][kv=(r&3)+8*(r>>2)+4*hi] ----
    f32x16 sacc = (f32x16){0.f,0.f,0.f,0.f,0.f,0.f,0.f,0.f,0.f,0.f,0.f,0.f,0.f,0.f,0.f,0.f};
    __builtin_amdgcn_s_setprio(1);
    #pragma unroll
    for (int ks=0; ks<16; ks++){
      int c = ks*2 + hi;
      short8 kf = *(const short8*)(Kc + lq*512 + ((c ^ (lq&7))<<4));
      sacc = __builtin_amdgcn_mfma_f32_32x32x16_bf16(kf, qf[ks], sacc, 0,0,0);
    }
    __builtin_amdgcn_s_setprio(0);

    // ---- online softmax, one q per lane ----
    float tmax = sacc[0];
    #pragma unroll
    for (int r=1;r<16;r++) tmax = fmaxf(tmax, sacc[r]);
    tmax *= 0.0625f;
    tmax = fmaxf(tmax, __shfl_xor(tmax, 32));
    if (!__all(tmax <= mrun + 8.f)){           // T13 defer-max
      float mn = fmaxf(mrun, tmax);
      float sc = __expf(mrun - mn);
      mrun = mn; ell *= sc;
      #pragma unroll
      for (int r=0;r<16;r++){
        float scr = __shfl(sc, (r&3)+8*(r>>2)+4*hi);
        #pragma unroll
        for (int dt=0; dt<8; dt++) o[dt][r] *= scr;
      }
    }

    // ---- P -> wave-private LDS at verified C-layout coords, then A-frag reads ----
    // lane (lq,hi), h half: p[r] = P[q=lq][kv = (r&3) + 8*(r>>2) + 4*hi + 16*h]
    float rs = 0.f;
    #pragma unroll
    for (int h=0; h<2; h++){
      float p[8];
      #pragma unroll
      for (int r=0;r<8;r++){ p[r] = __expf(sacc[h*8+r]*0.0625f - mrun); rs += p[r]; }
      uint2 w0, w1;
      w0.x = cvtpk_bf16(p[0], p[1]);  w0.y = cvtpk_bf16(p[2], p[3]);   // kv (0..3)+4hi+16h
      w1.x = cvtpk_bf16(p[4], p[5]);  w1.y = cvtpk_bf16(p[6], p[7]);   // kv (8..11)+4hi+16h
      *(uint2*)(PsW + lq*40 + h*16 + hi*4)     = w0;
      *(uint2*)(PsW + lq*40 + h*16 + 8 + hi*4) = w1;
    }
    rs += __shfl_xor(rs, 32);
    ell += rs;
    asm volatile("s_waitcnt lgkmcnt(0)" ::: "memory");
    __builtin_amdgcn_sched_barrier(0);
    short8 pa0 = *(const short8*)(PsW + lq*40 + hi*8);        // P[lq][hi*8 + 0..7]
    short8 pa1 = *(const short8*)(PsW + lq*40 + 16 + hi*8);   // P[lq][16 + hi*8 + 0..7]

    // ---- O += P @ V ----
    __builtin_amdgcn_s_setprio(1);
    #pragma unroll
    for (int dt=0; dt<8; dt++){
      short8 vf0 = *(const short8*)(Vc + (((hi  )*256 + dt*32 + lq)<<4));
      short8 vf1 = *(const short8*)(Vc + (((2+hi)*256 + dt*32 + lq)<<4));
      o[dt] = __builtin_amdgcn_mfma_f32_32x32x16_bf16(pa0, vf0, o[dt], 0,0,0);
      o[dt] = __builtin_amdgcn_mfma_f32_32x32x16_bf16(pa1, vf1, o[dt], 0,0,0);
    }
    __builtin_amdgcn_s_setprio(0);

    asm volatile("s_waitcnt vmcnt(0)" ::: "memory");
    __syncthreads();   // next tile staged + all waves done with cur
  }

  // ---- write partials (bf16) ----
  size_t rowb = (size_t)s*16384 + (size_t)b*NC + qb0;
  #pragma unroll
  for (int dt=0; dt<8; dt++)
    #pragma unroll
    for (int r=0;r<16;r++){
      int q = (r&3) + 8*(r>>2) + 4*hi;
      Opart[(rowb + q)*256 + dt*32 + lq] = f2b(o[dt][r]);
    }
  if (lane < 32){
    MLpart[(rowb + lane)*2]     = mrun;
    MLpart[(rowb + lane)*2 + 1] = ell;
  }
}

// ------- merge 4 split partials (bf16) + residual(xln) -> x2 ; fused LN2 -> h2 -----------
__global__ void __launch_bounds__(256) merge4_ln(const u16* __restrict__ Opart,
                                                 const float* __restrict__ MLpart,
                                                 const float* __restrict__ xln,
                                                 const float* __restrict__ g2,
                                                 const float* __restrict__ be2,
                                                 float* __restrict__ x2,
                                                 u16* __restrict__ h2){
  int row = blockIdx.x; int t = threadIdx.x;
  const size_t RS = 16384ull*256;
  float m[4], l[4];
  #pragma unroll
  for (int s=0;s<4;s++){
    m[s] = MLpart[((size_t)s*16384 + row)*2];
    l[s] = MLpart[((size_t)s*16384 + row)*2 + 1];
  }
  float M = fmaxf(fmaxf(m[0],m[1]), fmaxf(m[2],m[3]));
  float e[4]; float den = 0.f;
  #pragma unroll
  for (int s=0;s<4;s++){ e[s] = __expf(m[s]-M); den += l[s]*e[s]; }
  float inv = 1.0f/den;
  size_t idx = (size_t)row*256 + t;
  float v = 0.f;
  #pragma unroll
  for (int s=0;s<4;s++){
    unsigned u = Opart[(size_t)s*RS + idx];
    v += __uint_as_float(u << 16) * e[s];
  }
  v = v*inv + xln[idx];
  x2[idx] = v;
  // ---- fused LayerNorm over the row ----
  float s1 = v;
  #pragma unroll
  for (int mk=1;mk<64;mk<<=1) s1 += __shfl_xor(s1, mk);
  __shared__ float red[4];
  int w = t>>6;
  if ((t&63)==0) red[w] = s1;
  __syncthreads();
  float mean = (red[0]+red[1]+red[2]+red[3]) * (1.0f/256.0f);
  float d = v - mean;
  float s2 = d*d;
  #pragma unroll
  for (int mk=1;mk<64;mk<<=1) s2 += __shfl_xor(s2, mk);
  __syncthreads();
  if ((t&63)==0) red[w] = s2;
  __syncthreads();
  float var = (red[0]+red[1]+red[2]+red[3]) * (1.0f/256.0f);
  h2[idx] = f2b(d * rsqrtf(var + 1e-5f) * g2[t] + be2[t]);
}

extern "C" void kernel_launch(void* const* d_in, const int* in_sizes, int n_in,
                              void* d_out, int out_size, void* d_ws, size_t ws_size,
                              hipStream_t stream){
  const float* x   = (const float*)d_in[0];
  const float* g1  = (const float*)d_in[1];
  const float* be1 = (const float*)d_in[2];
  const float* wq  = (const float*)d_in[3];
  const float* bq  = (const float*)d_in[4];
  const float* wk  = (const float*)d_in[5];
  const float* bk  = (const float*)d_in[6];
  const float* wv  = (const float*)d_in[7];
  const float* bv  = (const float*)d_in[8];
  const float* g2  = (const float*)d_in[9];
  const float* be2 = (const float*)d_in[10];
  const float* w1  = (const float*)d_in[11];
  const float* bm1 = (const float*)d_in[12];
  const float* w2  = (const float*)d_in[13];
  const float* bm2 = (const float*)d_in[14];
  float* out = (float*)d_out;

  const size_t RS = 16384ull*256;
  char* p = (char*)d_ws;
  float* xln = (float*)p;  p += RS*4;            // 16 MiB; reused in-place as x2
  u16*  Op   = (u16*)p;    p += 4*RS*2;          // 32 MiB bf16 partials; reused as h1
  float* ML  = (float*)p;  p += 4*16384ull*2*4;  // 0.5 MiB
  u16* xb  = (u16*)p; p += RS*2;                 // 8 MiB
  u16* qb  = (u16*)p; p += RS*2;                 // 8 MiB; reused as h2 after flash
  u16* kb  = (u16*)p; p += RS*2;
  u16* vT  = (u16*)p; p += RS*2;
  u16* wqkvT = (u16*)p; p += 3*65536ull*2;
  u16* w1T = (u16*)p; p += 262144ull*2;
  u16* w2T = (u16*)p; p += 262144ull*2;
  float* x2 = xln;
  u16*   h1 = Op;
  u16*   h2 = qb;

  transpose_cast3<<<dim3(8,8,3), 256,0,stream>>>(wq, wk, wv, wqkvT);
  transpose_cast<<<dim3(8,32), 256,0,stream>>>(w1, w1T, 256, 1024);
  transpose_cast<<<dim3(32,8), 256,0,stream>>>(w2, w2T, 1024, 256);

  ln_kernel<<<16384,256,0,stream>>>(x, g1, be1, xln, xb);

  // fused QKV: qb, kb, V-granules in one GEMM
  gemm_bt<3><<<dim3(128,6),256,0,stream>>>(xb, wqkvT, bq, bk, bv, nullptr, nullptr,
                                           qb, kb, vT, 16384,768,256);

  flash_attn32<<<dim3(32,4,4),256,0,stream>>>(qb, kb, vT, Op, ML);
  merge4_ln<<<16384,256,0,stream>>>(Op, ML, xln, g2, be2, x2, h2);

  gemm_bt<1><<<dim3(128,8),256,0,stream>>>(h2, w1T, bm1, nullptr, nullptr, nullptr, nullptr,
                                           h1, nullptr, nullptr, 16384,1024,256);
  gemm_bt<2><<<dim3(128,2),256,0,stream>>>(h1, w2T, bm2, nullptr, nullptr, x2, out,
                                           nullptr, nullptr, nullptr, 16384,256,1024);
}